// Round 6
// baseline (94.443 us; speedup 1.0000x reference)
//
#include <hip/hip_runtime.h>

// LogSparseAttention: B=2, L=2048, H=8, E=D=64, S=2048. fp32 in/out.
// Mask row r: r<22 -> causal prefix 0..r; r>=22 -> window {r-10..r} +
// taps {r-10-2^i, i=0..10, >=0}. <=22 active keys -> 6 chunks of 4.
// R6: prep kernel packs K,V into bf16 interleaved rows in d_ws:
//   P[(b*H+h)*S+s] = [Kbf16 x64 | Vbf16 x64] = 256 B  (2 cache lines/key,
//   one dwordx4 per 16-lane group fetches K AND V for a key).
// Gather: wave = one (b,h,l) row, 4 groups x 16 lanes; group g owns key
// ordinal 4c+g; lane t<8 holds K elems [8t,8t+8), t>=8 holds V elems
// [8(t-8),...). Dot: K-lanes FMA, V-lanes add 0, 4-DPP tree replicates the
// sum to all 16 lanes (validated R4). Chain-free two-phase softmax (R4).

#define BB 2
#define LL 2048
#define HH 8
#define EE 64
#define SS 2048

__device__ __forceinline__ unsigned short bf16_rne(float f) {
    unsigned int u = __float_as_uint(f);
    unsigned int r = u + 0x7FFFu + ((u >> 16) & 1u);
    return (unsigned short)(r >> 16);
}

template<int CTRL>
__device__ __forceinline__ float dpp_add(float v) {
    int t = __builtin_amdgcn_mov_dpp(__float_as_int(v), CTRL, 0xF, 0xF, false);
    return v + __int_as_float(t);
}

__device__ __forceinline__ void unpack8(const uint4 kv, float* e) {
    e[0] = __int_as_float((int)(kv.x << 16));
    e[1] = __int_as_float((int)(kv.x & 0xFFFF0000u));
    e[2] = __int_as_float((int)(kv.y << 16));
    e[3] = __int_as_float((int)(kv.y & 0xFFFF0000u));
    e[4] = __int_as_float((int)(kv.z << 16));
    e[5] = __int_as_float((int)(kv.z & 0xFFFF0000u));
    e[6] = __int_as_float((int)(kv.w << 16));
    e[7] = __int_as_float((int)(kv.w & 0xFFFF0000u));
}

// ---- prep: K,V (b,s,h,e) fp32 -> P[(b*H+h)*S+s] bf16 interleaved ----
__global__ __launch_bounds__(256) void pack_kv_kernel(
    const float* __restrict__ K, const float* __restrict__ V,
    unsigned short* __restrict__ P)
{
    const int j = blockIdx.x * 256 + threadIdx.x;  // 0..262143, fully coalesced reads
    const int p = j & 7;
    const int h = (j >> 3) & (HH - 1);
    const int s = (j >> 6) & (SS - 1);
    const int b = j >> 17;
    const size_t src = (((size_t)b * SS + s) * HH + h) * EE + 8 * p;
    const float4 k0 = *(const float4*)(K + src);
    const float4 k1 = *(const float4*)(K + src + 4);
    const float4 v0 = *(const float4*)(V + src);
    const float4 v1 = *(const float4*)(V + src + 4);
    uint4 kw, vw;
    kw.x = bf16_rne(k0.x) | ((unsigned)bf16_rne(k0.y) << 16);
    kw.y = bf16_rne(k0.z) | ((unsigned)bf16_rne(k0.w) << 16);
    kw.z = bf16_rne(k1.x) | ((unsigned)bf16_rne(k1.y) << 16);
    kw.w = bf16_rne(k1.z) | ((unsigned)bf16_rne(k1.w) << 16);
    vw.x = bf16_rne(v0.x) | ((unsigned)bf16_rne(v0.y) << 16);
    vw.y = bf16_rne(v0.z) | ((unsigned)bf16_rne(v0.w) << 16);
    vw.z = bf16_rne(v1.x) | ((unsigned)bf16_rne(v1.y) << 16);
    vw.w = bf16_rne(v1.z) | ((unsigned)bf16_rne(v1.w) << 16);
    const size_t n = ((size_t)b * HH + h) * SS + s;  // packed row id
    *(uint4*)(P + n * 128 + 8 * p)      = kw;        // K half  (bytes [0,128))
    *(uint4*)(P + n * 128 + 64 + 8 * p) = vw;        // V half  (bytes [128,256))
}

// ---- gather ----
__global__ __launch_bounds__(256) void logsparse_attn_kernel(
    const float* __restrict__ Q,
    const unsigned short* __restrict__ P,
    float* __restrict__ O)
{
    const int lane = threadIdx.x & 63;
    const int wv   = threadIdx.x >> 6;
    // XCD swizzle (kept from R5; packed working set 1 MB per XCD-slice of L2)
    const int lb  = ((blockIdx.x & 7) << 10) | (blockIdx.x >> 3);
    const int row = lb * 4 + wv;
    const int l  = row % LL;
    const int bh = row / LL;

    const int t  = lane & 15;   // 0..7: K lanes, 8..15: V lanes
    const int g  = lane >> 4;   // key group 0..3
    const int t8 = t & 7;       // element-chunk index (dims 8*t8..8*t8+7)

    const size_t qbase = ((size_t)(bh / HH) * LL + l) * HH * EE + (size_t)(bh & (HH - 1)) * EE;
    float qr[8];
    {
        const float4 a  = *(const float4*)(Q + qbase + 8 * t8);
        const float4 b4 = *(const float4*)(Q + qbase + 8 * t8 + 4);
        qr[0] = a.x;  qr[1] = a.y;  qr[2] = a.z;  qr[3] = a.w;
        qr[4] = b4.x; qr[5] = b4.y; qr[6] = b4.z; qr[7] = b4.w;
    }

    const unsigned short* Pbh = P + (size_t)bh * SS * 128;

    // wave-uniform active-key bookkeeping
    int ntaps, nkeys, w0;
    if (l < 22) { ntaps = 0; nkeys = l + 1; w0 = 0; }
    else {
        w0 = l - 10;
        ntaps = 32 - __clz(w0);
        if (ntaps > 11) ntaps = 11;
        nkeys = ntaps + 11;
    }

    // phase 0: issue all 6 packed loads
    uint4 kv[6];
    #pragma unroll
    for (int c = 0; c < 6; ++c) {
        const int n  = 4 * c + g;
        const int nc = (n < nkeys) ? n : (nkeys - 1);
        int key;
        if (l < 22)           key = nc;
        else if (nc < ntaps)  key = w0 - (1 << (ntaps - 1 - nc));
        else                  key = w0 + (nc - ntaps);
        kv[c] = *(const uint4*)(Pbh + ((size_t)key << 7) + 8 * t);  // 16B/lane
    }

    // phase 1: dots (K lanes contribute, V lanes add 0; DPP tree -> all lanes)
    float sc[6];
    #pragma unroll
    for (int c = 0; c < 6; ++c) {
        float e[8];
        unpack8(kv[c], e);
        float p = qr[0]*e[0] + qr[1]*e[1] + qr[2]*e[2] + qr[3]*e[3]
                + qr[4]*e[4] + qr[5]*e[5] + qr[6]*e[6] + qr[7]*e[7];
        p = (t < 8) ? p : 0.0f;
        p = dpp_add<0xB1>(p);    // xor1
        p = dpp_add<0x4E>(p);    // xor2
        p = dpp_add<0x124>(p);   // row_ror:4
        p = dpp_add<0x128>(p);   // row_ror:8 -> 16-lane sum everywhere
        sc[c] = ((4 * c + g) < nkeys) ? p * 0.125f : -1e30f;
    }

    float mg = sc[0];
    #pragma unroll
    for (int c = 1; c < 6; ++c) mg = fmaxf(mg, sc[c]);

    // phase 2: weights + V accumulate (V lanes meaningful; K lanes garbage)
    float lsum = 0.0f;
    float acc[8] = {0.f,0.f,0.f,0.f,0.f,0.f,0.f,0.f};
    #pragma unroll
    for (int c = 0; c < 6; ++c) {
        const float w = __expf(sc[c] - mg);   // invalid: exp(-1e30-mg)=0
        lsum += w;
        float e[8];
        unpack8(kv[c], e);
        #pragma unroll
        for (int j = 0; j < 8; ++j) acc[j] += w * e[j];
    }

    // global max + rescale (fully-invalid group: r=0 annihilates garbage)
    float M = mg;
    M = fmaxf(M, __shfl_xor(M, 16, 64));
    M = fmaxf(M, __shfl_xor(M, 32, 64));
    const float r = __expf(mg - M);
    lsum *= r;
    #pragma unroll
    for (int j = 0; j < 8; ++j) acc[j] *= r;

    // cross-group combine (lane index within group preserved -> same dims)
    lsum += __shfl_xor(lsum, 16, 64);
    lsum += __shfl_xor(lsum, 32, 64);
    #pragma unroll
    for (int j = 0; j < 8; ++j) {
        acc[j] += __shfl_xor(acc[j], 16, 64);
        acc[j] += __shfl_xor(acc[j], 32, 64);
    }

    if (g == 0 && t >= 8) {
        const float inv = 1.0f / lsum;
        float4 o0, o1;
        o0.x = acc[0]*inv; o0.y = acc[1]*inv; o0.z = acc[2]*inv; o0.w = acc[3]*inv;
        o1.x = acc[4]*inv; o1.y = acc[5]*inv; o1.z = acc[6]*inv; o1.w = acc[7]*inv;
        *(float4*)(O + qbase + 8 * t8)     = o0;
        *(float4*)(O + qbase + 8 * t8 + 4) = o1;
    }
}

extern "C" void kernel_launch(void* const* d_in, const int* in_sizes, int n_in,
                              void* d_out, int out_size, void* d_ws, size_t ws_size,
                              hipStream_t stream) {
    const float* Q = (const float*)d_in[0];
    const float* K = (const float*)d_in[1];
    const float* V = (const float*)d_in[2];
    float* O = (float*)d_out;
    unsigned short* P = (unsigned short*)d_ws;   // 8 MB packed K/V

    // prep: 262144 threads, fully-coalesced reads, 128B-segment writes
    hipLaunchKernelGGL(pack_kv_kernel, dim3((BB*SS*HH*8)/256), dim3(256), 0, stream,
                       K, V, P);
    // gather: 8192 blocks x 4 waves
    hipLaunchKernelGGL(logsparse_attn_kernel, dim3((BB*HH*LL)/4), dim3(256), 0, stream,
                       Q, P, O);
}